// Round 7
// baseline (572.265 us; speedup 1.0000x reference)
//
#include <hip/hip_runtime.h>

// Problem constants
#define NB 10000          // batch
#define NC 64             // channels
#define NROWS (NB * NC)   // 640000 (b,c) rows
#define NE 10             // elements
#define DIN 40            // 1+3+9+27
#define NM 13             // 1+3+9 output m's
#define NPAIR 820         // 40*41/2 symmetric pairs
#define NBAND 20          // i-bands of 2
#define NSTEP 420         // sum_b (40-2b) (band,j) steps
#define XS 41             // LDS row stride for fallback kernel

#define XT_FLOATS (DIN * NROWS)                    // 25,600,000
#define PACK2_FLOATS (NSTEP * 32 + DIN * 16)       // 14,080
#define WS_NEED_BYTES ((size_t)(XT_FLOATS + PACK2_FLOATS) * 4)

// ---------------------------------------------------------------------------
// Pack kernel (primary path): band-2 layout. Step e <-> (band b, j), with
// offset(b) = b*(41-b), j = 2b + (e - offset(b)). Entry = 32 floats:
// [0..12]  coefs for pair (2b,   j)  (x2 off-diag, 0 if invalid)
// [16..28] coefs for pair (2b+1, j)  (0 when j < 2b+1)
// u1Pack ([40][16]) MUST follow immediately: the main loop's refill overruns
// into steps 420/421 (reads only, values never used in FMAs).
// ---------------------------------------------------------------------------
__global__ void psc_pack2_kernel(const float* __restrict__ U2_0,
                                 const float* __restrict__ U2_1,
                                 const float* __restrict__ U2_2,
                                 const float* __restrict__ U1_0,
                                 const float* __restrict__ U1_1,
                                 const float* __restrict__ U1_2,
                                 float* __restrict__ coefPack,   // [420][32]
                                 float* __restrict__ u1Pack)     // [40][16]
{
    int tid = blockIdx.x * blockDim.x + threadIdx.x;
    if (tid < NSTEP * 32) {
        int e  = tid >> 5;
        int s5 = tid & 31;
        int b = 0;
        while (b < NBAND - 1 && (b + 1) * (40 - b) <= e) ++b;  // offset(b+1)=(b+1)(40-b)
        int i0 = 2 * b;
        int j  = i0 + (e - b * (41 - b));
        int t  = s5 >> 4;          // pair-in-band
        int m  = s5 & 15;
        int i  = i0 + t;
        float v = 0.0f;
        if (m < NM && i <= j) {
            float s = (i == j) ? 1.0f : 2.0f;
            if (m == 0)      v = U2_0[i * 40 + j] * s;
            else if (m < 4)  v = U2_1[(m - 1) * 1600 + i * 40 + j] * s;
            else             v = U2_2[(m - 4) * 1600 + i * 40 + j] * s;
        }
        coefPack[e * 32 + s5] = v;
    } else if (tid < NSTEP * 32 + DIN * 16) {
        int t = tid - NSTEP * 32;
        int m = t & 15;
        int i = t >> 4;
        float v = 0.0f;
        if (m == 0)       v = U1_0[i];
        else if (m < 4)   v = U1_1[(m - 1) * 40 + i];
        else if (m < 13)  v = U1_2[(m - 4) * 40 + i];
        u1Pack[i * 16 + m] = v;
    }
}

// ---------------------------------------------------------------------------
// Transpose features into xT[j][bc]. Writes coalesced; reads L2-absorbed.
// ---------------------------------------------------------------------------
__global__ void psc_transpose_kernel(const float* __restrict__ f0,
                                     const float* __restrict__ f1,
                                     const float* __restrict__ f2,
                                     const float* __restrict__ f3,
                                     float* __restrict__ xT)
{
    int bc = blockIdx.x * 256 + threadIdx.x;
    if (bc >= NROWS) return;
    xT[bc] = f0[bc];
    #pragma unroll
    for (int k = 0; k < 3; ++k)  xT[(1 + k)  * NROWS + bc] = f1[bc * 3 + k];
    #pragma unroll
    for (int k = 0; k < 9; ++k)  xT[(4 + k)  * NROWS + bc] = f2[bc * 9 + k];
    #pragma unroll
    for (int k = 0; k < 27; ++k) xT[(13 + k) * NROWS + bc] = f3[bc * 27 + k];
}

// 13 FMAs into acc2[R][*] from 4 float4 coefficient regs
#define FMA13R(R, Q0, Q1, Q2, Q3, XX)                                   \
    acc2[R][0]  += (Q0).x * (XX);  acc2[R][1]  += (Q0).y * (XX);        \
    acc2[R][2]  += (Q0).z * (XX);  acc2[R][3]  += (Q0).w * (XX);        \
    acc2[R][4]  += (Q1).x * (XX);  acc2[R][5]  += (Q1).y * (XX);        \
    acc2[R][6]  += (Q1).z * (XX);  acc2[R][7]  += (Q1).w * (XX);        \
    acc2[R][8]  += (Q2).x * (XX);  acc2[R][9]  += (Q2).y * (XX);        \
    acc2[R][10] += (Q2).z * (XX);  acc2[R][11] += (Q2).w * (XX);        \
    acc2[R][12] += (Q3).x * (XX);

// advance wave-uniform prefetch position (bp, jp); refresh band xi registers
// on band change. Clamps at the last band (overrun reads stay in-bounds).
#define ADVB()                                                          \
    do {                                                                \
        ++jp;                                                           \
        if (jp >= DIN) {                                                \
            if (bp < NBAND - 1) ++bp;                                   \
            jp = 2 * bp;                                                \
            const float* q0_ = xT + (2 * bp) * NROWS + bc0;             \
            const float* q1_ = xT + (2 * bp + 1) * NROWS + bc0;         \
            xiP00 = q0_[lane]; xiP01 = q0_[lane + 64];                  \
            xiP10 = q1_[lane]; xiP11 = q1_[lane + 64];                  \
        }                                                               \
    } while (0)

// load one (band,j) step into a phase's registers, then advance
#define STEP_LOAD(C0_, C1_, C2_, C3_, C4_, C5_, C6_, C7_,               \
                  XI00, XI01, XI10, XI11, XJ0, XJ1)                     \
    do {                                                                \
        C0_ = cp4[0]; C1_ = cp4[1]; C2_ = cp4[2]; C3_ = cp4[3];         \
        C4_ = cp4[4]; C5_ = cp4[5]; C6_ = cp4[6]; C7_ = cp4[7];         \
        const float* pj_ = xT + jp * NROWS + bc0;                       \
        XJ0 = pj_[lane]; XJ1 = pj_[lane + 64];                          \
        XI00 = xiP00; XI01 = xiP01; XI10 = xiP10; XI11 = xiP11;         \
        ADVB();                                                         \
        cp4 += 8;                                                       \
    } while (0)

// compute one step: 4 cross-products, 52 FMAs (2 pairs x 13 m x 2 rows)
#define STEP_COMPUTE(C0_, C1_, C2_, C3_, C4_, C5_, C6_, C7_,            \
                     XI00, XI01, XI10, XI11, XJ0, XJ1)                  \
    do {                                                                \
        float xx00 = (XI00) * (XJ0), xx01 = (XI01) * (XJ1);             \
        float xx10 = (XI10) * (XJ0), xx11 = (XI11) * (XJ1);             \
        FMA13R(0, C0_, C1_, C2_, C3_, xx00);                            \
        FMA13R(1, C0_, C1_, C2_, C3_, xx01);                            \
        FMA13R(0, C4_, C5_, C6_, C7_, xx10);                            \
        FMA13R(1, C4_, C5_, C6_, C7_, xx11);                            \
    } while (0)

// ---------------------------------------------------------------------------
// Main kernel (primary): band-2 tiled, transposed-x. Block = 128 threads =
// 2 waves; each wave owns 128 rows (2 b's x 64 ch, R=2 rows/lane).
// Per step: 1 x_j load (512 B/wave, vmcnt) + 8 uniform coef float4s
// (scalarizable, lgkmcnt) serve 52 FMAs; 1-step double-buffer covers latency.
// LDS 13 KB (basis transpose only) -> 12 blocks/CU LDS-limit.
// ---------------------------------------------------------------------------
__global__ __launch_bounds__(128, 5)
void psc_main_xt(const float* __restrict__ xT,
                 const float* __restrict__ attrs,
                 const float* __restrict__ W1_0, const float* __restrict__ W2_0,
                 const float* __restrict__ Wlin_0, const float* __restrict__ sc_0,
                 const float* __restrict__ W1_1, const float* __restrict__ W2_1,
                 const float* __restrict__ Wlin_1, const float* __restrict__ sc_1,
                 const float* __restrict__ W1_2, const float* __restrict__ W2_2,
                 const float* __restrict__ Wlin_2, const float* __restrict__ sc_2,
                 const float* __restrict__ coefPack,
                 const float* __restrict__ u1Pack,
                 float* __restrict__ out)
{
    __shared__ float bsT[2][2][NM][64];       // [wave][row][m][c], 13312 B

    const int lane = threadIdx.x & 63;
    const int wid  = threadIdx.x >> 6;
    const int bc0  = blockIdx.x * 256 + wid * 128;  // first row of this wave
    const int b0   = bc0 >> 6;                      // wave covers b0, b0+1

    // ---- a2: band-2 symmetric contraction, double-buffered steps ----------
    float acc2[2][NM];
    #pragma unroll
    for (int m = 0; m < NM; ++m) { acc2[0][m] = 0.f; acc2[1][m] = 0.f; }

    {
        const float4* cp4 = (const float4*)coefPack;
        int bp = 0, jp = 0;                   // wave-uniform prefetch position
        const float* q0 = xT + bc0;
        const float* q1 = xT + NROWS + bc0;
        float xiP00 = q0[lane], xiP01 = q0[lane + 64];
        float xiP10 = q1[lane], xiP11 = q1[lane + 64];

        float4 A0, A1, A2, A3, A4, A5, A6, A7;
        float  axi00, axi01, axi10, axi11, axj0, axj1;
        float4 B0, B1, B2, B3, B4, B5, B6, B7;
        float  bxi00, bxi01, bxi10, bxi11, bxj0, bxj1;

        STEP_LOAD(A0, A1, A2, A3, A4, A5, A6, A7,
                  axi00, axi01, axi10, axi11, axj0, axj1);   // step 0
        STEP_LOAD(B0, B1, B2, B3, B4, B5, B6, B7,
                  bxi00, bxi01, bxi10, bxi11, bxj0, bxj1);   // step 1

        for (int k = 0; k < NSTEP / 2; ++k) {                // 210 iters
            STEP_COMPUTE(A0, A1, A2, A3, A4, A5, A6, A7,
                         axi00, axi01, axi10, axi11, axj0, axj1);  // step 2k
            STEP_LOAD(A0, A1, A2, A3, A4, A5, A6, A7,
                      axi00, axi01, axi10, axi11, axj0, axj1);     // step 2k+2
            STEP_COMPUTE(B0, B1, B2, B3, B4, B5, B6, B7,
                         bxi00, bxi01, bxi10, bxi11, bxj0, bxj1);  // step 2k+1
            STEP_LOAD(B0, B1, B2, B3, B4, B5, B6, B7,
                      bxi00, bxi01, bxi10, bxi11, bxj0, bxj1);     // step 2k+3
        }
        // steps 0..419 all computed; final refills (420/421) read into dead
        // registers from u1Pack region -- in-bounds, never used.
    }

    // ---- a1: u1 contraction (40 x 13 per row) -----------------------------
    float a1[2][NM];
    #pragma unroll
    for (int m = 0; m < NM; ++m) { a1[0][m] = 0.f; a1[1][m] = 0.f; }
    #pragma unroll 4
    for (int i = 0; i < DIN; ++i) {
        const float* qi = xT + i * NROWS + bc0;
        float xi0 = qi[lane], xi1 = qi[lane + 64];
        const float4* u4 = (const float4*)&u1Pack[i * 16];
        float4 u0 = u4[0], u1v = u4[1], u2v = u4[2], u3v = u4[3];
        a1[0][0]  += u0.x  * xi0;  a1[1][0]  += u0.x  * xi1;
        a1[0][1]  += u0.y  * xi0;  a1[1][1]  += u0.y  * xi1;
        a1[0][2]  += u0.z  * xi0;  a1[1][2]  += u0.z  * xi1;
        a1[0][3]  += u0.w  * xi0;  a1[1][3]  += u0.w  * xi1;
        a1[0][4]  += u1v.x * xi0;  a1[1][4]  += u1v.x * xi1;
        a1[0][5]  += u1v.y * xi0;  a1[1][5]  += u1v.y * xi1;
        a1[0][6]  += u1v.z * xi0;  a1[1][6]  += u1v.z * xi1;
        a1[0][7]  += u1v.w * xi0;  a1[1][7]  += u1v.w * xi1;
        a1[0][8]  += u2v.x * xi0;  a1[1][8]  += u2v.x * xi1;
        a1[0][9]  += u2v.y * xi0;  a1[1][9]  += u2v.y * xi1;
        a1[0][10] += u2v.z * xi0;  a1[1][10] += u2v.z * xi1;
        a1[0][11] += u2v.w * xi0;  a1[1][11] += u2v.w * xi1;
        a1[0][12] += u3v.x * xi0;  a1[1][12] += u3v.x * xi1;
    }

    // ---- element-aware channel weights (W loads shared across both rows) --
    float w1a0 = 0.f, w1a1 = 0.f, w1a2 = 0.f, w2a0 = 0.f, w2a1 = 0.f, w2a2 = 0.f;
    float w1b0 = 0.f, w1b1 = 0.f, w1b2 = 0.f, w2b0 = 0.f, w2b1 = 0.f, w2b2 = 0.f;
    #pragma unroll
    for (int e = 0; e < NE; ++e) {
        float va = attrs[b0 * NE + e];          // wave-uniform -> s_load
        float vb = attrs[(b0 + 1) * NE + e];
        float x10 = W1_0[e * 64 + lane], x20 = W2_0[e * 64 + lane];
        float x11 = W1_1[e * 64 + lane], x21 = W2_1[e * 64 + lane];
        float x12 = W1_2[e * 64 + lane], x22 = W2_2[e * 64 + lane];
        w1a0 += va * x10;  w1b0 += vb * x10;
        w2a0 += va * x20;  w2b0 += vb * x20;
        w1a1 += va * x11;  w1b1 += vb * x11;
        w2a1 += va * x21;  w2b1 += vb * x21;
        w1a2 += va * x12;  w1b2 += vb * x12;
        w2a2 += va * x22;  w2b2 += vb * x22;
    }

    // ---- basis = a1*w1 + a2*w2, transpose through LDS ----------------------
    bsT[wid][0][0][lane] = a1[0][0] * w1a0 + acc2[0][0] * w2a0;
    bsT[wid][1][0][lane] = a1[1][0] * w1b0 + acc2[1][0] * w2b0;
    #pragma unroll
    for (int m = 1; m < 4; ++m) {
        bsT[wid][0][m][lane] = a1[0][m] * w1a1 + acc2[0][m] * w2a1;
        bsT[wid][1][m][lane] = a1[1][m] * w1b1 + acc2[1][m] * w2b1;
    }
    #pragma unroll
    for (int m = 4; m < NM; ++m) {
        bsT[wid][0][m][lane] = a1[0][m] * w1a2 + acc2[0][m] * w2a2;
        bsT[wid][1][m][lane] = a1[1][m] * w1b2 + acc2[1][m] * w2b2;
    }
    __syncthreads();

    // ---- channel mix: om[r][m] = sum_cc bsT[wid][r][m][cc] * Wlin_l[cc,o] --
    const int o = lane;
    float om[2][NM];
    #pragma unroll
    for (int m = 0; m < NM; ++m) { om[0][m] = 0.f; om[1][m] = 0.f; }

    for (int c4 = 0; c4 < 16; ++c4) {
        const int cc = c4 * 4;
        float p0 = Wlin_0[(cc + 0) * 64 + o], p1 = Wlin_0[(cc + 1) * 64 + o],
              p2 = Wlin_0[(cc + 2) * 64 + o], p3 = Wlin_0[(cc + 3) * 64 + o];
        float q0 = Wlin_1[(cc + 0) * 64 + o], q1 = Wlin_1[(cc + 1) * 64 + o],
              q2 = Wlin_1[(cc + 2) * 64 + o], q3 = Wlin_1[(cc + 3) * 64 + o];
        float r0 = Wlin_2[(cc + 0) * 64 + o], r1 = Wlin_2[(cc + 1) * 64 + o],
              r2 = Wlin_2[(cc + 2) * 64 + o], r3 = Wlin_2[(cc + 3) * 64 + o];

        #pragma unroll
        for (int r = 0; r < 2; ++r) {
            float4 t;
            t = *(const float4*)&bsT[wid][r][0][cc];
            om[r][0] += t.x * p0 + t.y * p1 + t.z * p2 + t.w * p3;
            #pragma unroll
            for (int m = 1; m < 4; ++m) {
                t = *(const float4*)&bsT[wid][r][m][cc];
                om[r][m] += t.x * q0 + t.y * q1 + t.z * q2 + t.w * q3;
            }
            #pragma unroll
            for (int m = 4; m < NM; ++m) {
                t = *(const float4*)&bsT[wid][r][m][cc];
                om[r][m] += t.x * r0 + t.y * r1 + t.z * r2 + t.w * r3;
            }
        }
    }

    // ---- add skip connection, write outputs (tuple concat layout) ---------
    #pragma unroll
    for (int r = 0; r < 2; ++r) {
        const int bo = bc0 + r * 64 + lane;     // == b*64 + c
        out[bo] = om[r][0] + sc_0[bo];
        #pragma unroll
        for (int k = 0; k < 3; ++k)
            out[NROWS + bo * 3 + k] = om[r][1 + k] + sc_1[bo * 3 + k];
        #pragma unroll
        for (int k = 0; k < 9; ++k)
            out[NROWS * 4 + bo * 9 + k] = om[r][4 + k] + sc_2[bo * 9 + k];
    }
}

// ---------------------------------------------------------------------------
// Fallback path (proven 438 us, measured R4): old pack layout + LDS-staged x.
// ---------------------------------------------------------------------------
__global__ void psc_pack_kernel(const float* __restrict__ U2_0,
                                const float* __restrict__ U2_1,
                                const float* __restrict__ U2_2,
                                const float* __restrict__ U1_0,
                                const float* __restrict__ U1_1,
                                const float* __restrict__ U1_2,
                                float* __restrict__ coefPack,   // [820][16]
                                float* __restrict__ u1Pack)     // [40][16]
{
    int tid = blockIdx.x * blockDim.x + threadIdx.x;
    if (tid < 1600 * 16) {
        int m = tid & 15;
        int idx = tid >> 4;
        int i = idx / 40, j = idx % 40;
        if (j < i) return;
        int p = i * 40 - ((i * (i - 1)) >> 1) + (j - i);
        float s = (i == j) ? 1.0f : 2.0f;
        float v = 0.0f;
        if (m == 0)       v = U2_0[i * 40 + j];
        else if (m < 4)   v = U2_1[(m - 1) * 1600 + i * 40 + j];
        else if (m < 13)  v = U2_2[(m - 4) * 1600 + i * 40 + j];
        coefPack[p * 16 + m] = v * s;
    } else if (tid < 1600 * 16 + 40 * 16) {
        int t = tid - 1600 * 16;
        int m = t & 15;
        int i = t >> 4;
        float v = 0.0f;
        if (m == 0)       v = U1_0[i];
        else if (m < 4)   v = U1_1[(m - 1) * 40 + i];
        else if (m < 13)  v = U1_2[(m - 4) * 40 + i];
        u1Pack[i * 16 + m] = v;
    }
}

#define FMA13(Q0, Q1, Q2, Q3, XX)                                     \
    acc2[0]  += (Q0).x * (XX);  acc2[1]  += (Q0).y * (XX);            \
    acc2[2]  += (Q0).z * (XX);  acc2[3]  += (Q0).w * (XX);            \
    acc2[4]  += (Q1).x * (XX);  acc2[5]  += (Q1).y * (XX);            \
    acc2[6]  += (Q1).z * (XX);  acc2[7]  += (Q1).w * (XX);            \
    acc2[8]  += (Q2).x * (XX);  acc2[9]  += (Q2).y * (XX);            \
    acc2[10] += (Q2).z * (XX);  acc2[11] += (Q2).w * (XX);            \
    acc2[12] += (Q3).x * (XX);

#define ADV()                                                         \
    do {                                                              \
        ++jp;                                                         \
        if (jp >= DIN) {                                              \
            if (ip < DIN - 1) ++ip;                                   \
            jp = ip;                                                  \
            xip = xrow[ip];                                           \
        }                                                             \
    } while (0)

__global__ __launch_bounds__(64, 4)
void psc_main_lds(const float* __restrict__ f0, const float* __restrict__ f1,
                  const float* __restrict__ f2, const float* __restrict__ f3,
                  const float* __restrict__ attrs,
                  const float* __restrict__ W1_0, const float* __restrict__ W2_0,
                  const float* __restrict__ Wlin_0, const float* __restrict__ sc_0,
                  const float* __restrict__ W1_1, const float* __restrict__ W2_1,
                  const float* __restrict__ Wlin_1, const float* __restrict__ sc_1,
                  const float* __restrict__ W1_2, const float* __restrict__ W2_2,
                  const float* __restrict__ Wlin_2, const float* __restrict__ sc_2,
                  const float* __restrict__ coefPack,
                  const float* __restrict__ u1Pack,
                  float* __restrict__ out)
{
    __shared__ float xs[64 * XS];

    const int c = threadIdx.x;
    const int b = blockIdx.x;

    xs[c * XS + 0] = f0[b * 64 + c];
    #pragma unroll
    for (int t = 0; t < 3; ++t) {
        int idx = c + 64 * t;
        int cc = idx / 3, k = idx % 3;
        xs[cc * XS + 1 + k] = f1[b * 192 + idx];
    }
    #pragma unroll
    for (int t = 0; t < 9; ++t) {
        int idx = c + 64 * t;
        int cc = idx / 9, k = idx % 9;
        xs[cc * XS + 4 + k] = f2[b * 576 + idx];
    }
    #pragma unroll
    for (int t = 0; t < 27; ++t) {
        int idx = c + 64 * t;
        int cc = idx / 27, k = idx % 27;
        xs[cc * XS + 13 + k] = f3[b * 1728 + idx];
    }
    __syncthreads();

    float w1l0 = 0.f, w2l0 = 0.f, w1l1 = 0.f, w2l1 = 0.f, w1l2 = 0.f, w2l2 = 0.f;
    #pragma unroll
    for (int e = 0; e < NE; ++e) {
        float a = attrs[b * NE + e];
        w1l0 += a * W1_0[e * 64 + c];
        w2l0 += a * W2_0[e * 64 + c];
        w1l1 += a * W1_1[e * 64 + c];
        w2l1 += a * W2_1[e * 64 + c];
        w1l2 += a * W1_2[e * 64 + c];
        w2l2 += a * W2_2[e * 64 + c];
    }

    const float* xrow = &xs[c * XS];

    float acc1[NM];
    #pragma unroll
    for (int m = 0; m < NM; ++m) acc1[m] = 0.f;
    #pragma unroll 4
    for (int i = 0; i < DIN; ++i) {
        float xi = xrow[i];
        const float4* u4 = (const float4*)&u1Pack[i * 16];
        float4 u0 = u4[0], u1v = u4[1], u2v = u4[2], u3v = u4[3];
        acc1[0]  += u0.x  * xi;  acc1[1]  += u0.y  * xi;
        acc1[2]  += u0.z  * xi;  acc1[3]  += u0.w  * xi;
        acc1[4]  += u1v.x * xi;  acc1[5]  += u1v.y * xi;
        acc1[6]  += u1v.z * xi;  acc1[7]  += u1v.w * xi;
        acc1[8]  += u2v.x * xi;  acc1[9]  += u2v.y * xi;
        acc1[10] += u2v.z * xi;  acc1[11] += u2v.w * xi;
        acc1[12] += u3v.x * xi;
    }

    float acc2[NM];
    #pragma unroll
    for (int m = 0; m < NM; ++m) acc2[m] = 0.f;

    {
        const float4* cp4 = (const float4*)coefPack;
        int ip = 0, jp = 0;
        float xip = xrow[0];

        float4 A0 = cp4[0], A1 = cp4[1], A2 = cp4[2], A3 = cp4[3];
        float  xiA = xip, xjA = xrow[jp];
        ADV();
        float4 B0 = cp4[4], B1 = cp4[5], B2 = cp4[6], B3 = cp4[7];
        float  xiB = xip, xjB = xrow[jp];
        ADV();
        float4 C0 = cp4[8], C1 = cp4[9], C2 = cp4[10], C3 = cp4[11];
        float  xiC = xip, xjC = xrow[jp];
        ADV();
        cp4 += 12;

        for (int k = 0; k < NPAIR / 3; ++k) {
            float xx = xiA * xjA;
            FMA13(A0, A1, A2, A3, xx);
            A0 = cp4[0]; A1 = cp4[1]; A2 = cp4[2]; A3 = cp4[3];
            xiA = xip; xjA = xrow[jp];
            ADV();

            xx = xiB * xjB;
            FMA13(B0, B1, B2, B3, xx);
            B0 = cp4[4]; B1 = cp4[5]; B2 = cp4[6]; B3 = cp4[7];
            xiB = xip; xjB = xrow[jp];
            ADV();

            xx = xiC * xjC;
            FMA13(C0, C1, C2, C3, xx);
            C0 = cp4[8]; C1 = cp4[9]; C2 = cp4[10]; C3 = cp4[11];
            xiC = xip; xjC = xrow[jp];
            ADV();

            cp4 += 12;
        }
        float xx = xiA * xjA;
        FMA13(A0, A1, A2, A3, xx);
    }

    float basisv[NM];
    basisv[0] = acc1[0] * w1l0 + acc2[0] * w2l0;
    #pragma unroll
    for (int m = 1; m < 4; ++m)  basisv[m] = acc1[m] * w1l1 + acc2[m] * w2l1;
    #pragma unroll
    for (int m = 4; m < NM; ++m) basisv[m] = acc1[m] * w1l2 + acc2[m] * w2l2;

    __syncthreads();
    #pragma unroll
    for (int m = 0; m < NM; ++m)
        xs[m * 64 + c] = basisv[m];
    __syncthreads();

    const int o = c;
    float om[NM];
    #pragma unroll
    for (int m = 0; m < NM; ++m) om[m] = 0.f;

    for (int c4 = 0; c4 < 16; ++c4) {
        const int cc = c4 * 4;
        float p0 = Wlin_0[(cc + 0) * 64 + o], p1 = Wlin_0[(cc + 1) * 64 + o],
              p2 = Wlin_0[(cc + 2) * 64 + o], p3 = Wlin_0[(cc + 3) * 64 + o];
        float q0 = Wlin_1[(cc + 0) * 64 + o], q1 = Wlin_1[(cc + 1) * 64 + o],
              q2 = Wlin_1[(cc + 2) * 64 + o], q3 = Wlin_1[(cc + 3) * 64 + o];
        float r0 = Wlin_2[(cc + 0) * 64 + o], r1 = Wlin_2[(cc + 1) * 64 + o],
              r2 = Wlin_2[(cc + 2) * 64 + o], r3 = Wlin_2[(cc + 3) * 64 + o];

        float4 t;
        t = *(const float4*)&xs[0 * 64 + cc];
        om[0] += t.x * p0 + t.y * p1 + t.z * p2 + t.w * p3;
        #pragma unroll
        for (int m = 1; m < 4; ++m) {
            t = *(const float4*)&xs[m * 64 + cc];
            om[m] += t.x * q0 + t.y * q1 + t.z * q2 + t.w * q3;
        }
        #pragma unroll
        for (int m = 4; m < NM; ++m) {
            t = *(const float4*)&xs[m * 64 + cc];
            om[m] += t.x * r0 + t.y * r1 + t.z * r2 + t.w * r3;
        }
    }

    const int bo = b * 64 + o;
    out[bo] = om[0] + sc_0[bo];
    #pragma unroll
    for (int k = 0; k < 3; ++k)
        out[NB * 64 + bo * 3 + k] = om[1 + k] + sc_1[bo * 3 + k];
    #pragma unroll
    for (int k = 0; k < 9; ++k)
        out[NB * 64 * 4 + bo * 9 + k] = om[4 + k] + sc_2[bo * 9 + k];
}

// ---------------------------------------------------------------------------
extern "C" void kernel_launch(void* const* d_in, const int* in_sizes, int n_in,
                              void* d_out, int out_size, void* d_ws, size_t ws_size,
                              hipStream_t stream) {
    const float* f0    = (const float*)d_in[0];
    const float* f1    = (const float*)d_in[1];
    const float* f2    = (const float*)d_in[2];
    const float* f3    = (const float*)d_in[3];
    const float* attrs = (const float*)d_in[4];
    const float* U2_0  = (const float*)d_in[5];
    const float* U1_0  = (const float*)d_in[6];
    const float* W1_0  = (const float*)d_in[7];
    const float* W2_0  = (const float*)d_in[8];
    const float* Wl_0  = (const float*)d_in[9];
    const float* sc_0  = (const float*)d_in[10];
    const float* U2_1  = (const float*)d_in[11];
    const float* U1_1  = (const float*)d_in[12];
    const float* W1_1  = (const float*)d_in[13];
    const float* W2_1  = (const float*)d_in[14];
    const float* Wl_1  = (const float*)d_in[15];
    const float* sc_1  = (const float*)d_in[16];
    const float* U2_2  = (const float*)d_in[17];
    const float* U1_2  = (const float*)d_in[18];
    const float* W1_2  = (const float*)d_in[19];
    const float* W2_2  = (const float*)d_in[20];
    const float* Wl_2  = (const float*)d_in[21];
    const float* sc_2  = (const float*)d_in[22];
    float* out = (float*)d_out;

    if (ws_size >= WS_NEED_BYTES) {
        // primary path: band-2 pack + transpose + tiled main kernel
        float* xT       = (float*)d_ws;
        float* coefPack = xT + XT_FLOATS;
        float* u1Pack   = coefPack + NSTEP * 32;

        int packThreads = NSTEP * 32 + DIN * 16;
        psc_pack2_kernel<<<(packThreads + 255) / 256, 256, 0, stream>>>(
            U2_0, U2_1, U2_2, U1_0, U1_1, U1_2, coefPack, u1Pack);
        psc_transpose_kernel<<<NROWS / 256, 256, 0, stream>>>(f0, f1, f2, f3, xT);
        psc_main_xt<<<NROWS / 256, 128, 0, stream>>>(
            xT, attrs,
            W1_0, W2_0, Wl_0, sc_0,
            W1_1, W2_1, Wl_1, sc_1,
            W1_2, W2_2, Wl_2, sc_2,
            coefPack, u1Pack, out);
    } else {
        // fallback: proven LDS-staged kernel (438 us measured)
        float* coefPack = (float*)d_ws;
        float* u1Pack   = coefPack + NPAIR * 16;

        int packThreads = 1600 * 16 + 40 * 16;
        psc_pack_kernel<<<(packThreads + 255) / 256, 256, 0, stream>>>(
            U2_0, U2_1, U2_2, U1_0, U1_1, U1_2, coefPack, u1Pack);
        psc_main_lds<<<NB, 64, 0, stream>>>(
            f0, f1, f2, f3, attrs,
            W1_0, W2_0, Wl_0, sc_0,
            W1_1, W2_1, Wl_1, sc_1,
            W1_2, W2_2, Wl_2, sc_2,
            coefPack, u1Pack, out);
    }
}